// Round 5
// baseline (379.472 us; speedup 1.0000x reference)
//
#include <hip/hip_runtime.h>

#define HH 1024
#define WW 1024
#define BH 64              // output rows per block -> 16 strips x 48 images = 768 blocks
#define RAD 4
#define NSTRIP (HH / BH)   // 16

struct HS { float h0, h1, h2, h3; };

// 9-wide clipped horizontal sums for 4 consecutive columns from 3 overlapping
// float4 loads (L1/L2 absorb the 3x request amplification; HBM fetch ~1x).
__device__ __forceinline__ HS hcompute(float4 a, float4 b, float4 d) {
    HS h;
    h.h0 = ((a.x + a.y) + (a.z + a.w)) + ((b.x + b.y) + (b.z + b.w)) + d.x;
    h.h1 = h.h0 - a.x + d.y;
    h.h2 = h.h1 - a.y + d.z;
    h.h3 = h.h2 - a.z + d.w;
    return h;
}

#define LOADROW(pa, pb, pd, rowptr) do {                                   \
    pb = *(const float4*)((rowptr) + c);                                   \
    pa = first ? z4 : *(const float4*)((rowptr) + c - 4);                  \
    pd = last  ? z4 : *(const float4*)((rowptr) + c + 4);                  \
} while (0)

// batch-issue 12 independent loads: rows rowp..rowp+3 into register set S
#define LOADG(S) do {                                                      \
    LOADROW(a##S##0, b##S##0, d##S##0, rowp); rowp += WW;                  \
    LOADROW(a##S##1, b##S##1, d##S##1, rowp); rowp += WW;                  \
    LOADROW(a##S##2, b##S##2, d##S##2, rowp); rowp += WW;                  \
    LOADROW(a##S##3, b##S##3, d##S##3, rowp); rowp += WW;                  \
} while (0)

// boundary variant: clamp row index (validity handled at consume)
#define LOADGB(S) do {                                                     \
    const float* rp;                                                       \
    rp = xin + (size_t)(prow < HH ? prow : (HH - 1)) * WW; ++prow;         \
    LOADROW(a##S##0, b##S##0, d##S##0, rp);                                \
    rp = xin + (size_t)(prow < HH ? prow : (HH - 1)) * WW; ++prow;         \
    LOADROW(a##S##1, b##S##1, d##S##1, rp);                                \
    rp = xin + (size_t)(prow < HH ? prow : (HH - 1)) * WW; ++prow;         \
    LOADROW(a##S##2, b##S##2, d##S##2, rp);                                \
    rp = xin + (size_t)(prow < HH ? prow : (HH - 1)) * WW; ++prow;         \
    LOADROW(a##S##3, b##S##3, d##S##3, rp);                                \
} while (0)

// interior consume: one output row from set S element K.
// ring lives in LDS with a RUNTIME slot (LDS indexing is fine at runtime;
// only register arrays need static indices), every slot thread-private.
#define CONS1(S, K) do {                                                   \
    HS h = hcompute(a##S##K, b##S##K, d##S##K);                            \
    float4 hold = hring[slot][tid];                                        \
    vs0 += h.h0 - hold.x; vs1 += h.h1 - hold.y;                            \
    vs2 += h.h2 - hold.z; vs3 += h.h3 - hold.w;                            \
    hring[slot][tid] = make_float4(h.h0, h.h1, h.h2, h.h3);                \
    slot = (slot == 8) ? 0 : slot + 1;                                     \
    *(float4*)op = make_float4(vs0 * w0, vs1 * w1, vs2 * w2, vs3 * w3);    \
    op += WW;                                                              \
} while (0)
#define CONSG(S) do { CONS1(S,0); CONS1(S,1); CONS1(S,2); CONS1(S,3); } while (0)

// boundary consume: + row-validity zeroing and per-row vertical count
#define CONS1B(S, K) do {                                                  \
    HS h = hcompute(a##S##K, b##S##K, d##S##K);                            \
    if (r + RAD >= HH) { h.h0 = 0.f; h.h1 = 0.f; h.h2 = 0.f; h.h3 = 0.f; } \
    float4 hold = hring[slot][tid];                                        \
    vs0 += h.h0 - hold.x; vs1 += h.h1 - hold.y;                            \
    vs2 += h.h2 - hold.z; vs3 += h.h3 - hold.w;                            \
    hring[slot][tid] = make_float4(h.h0, h.h1, h.h2, h.h3);                \
    slot = (slot == 8) ? 0 : slot + 1;                                     \
    int lo = r - RAD; lo = lo < 0 ? 0 : lo;                                \
    int hi = r + RAD; hi = hi > HH - 1 ? HH - 1 : hi;                      \
    float ich = 1.0f / (float)(hi - lo + 1);                               \
    *(float4*)op = make_float4(vs0 * ich * sw[0], vs1 * ich * sw[1],       \
                               vs2 * ich * sw[2], vs3 * ich * sw[3]);      \
    op += WW; ++r;                                                         \
} while (0)
#define CONSGB(S) do { CONS1B(S,0); CONS1B(S,1); CONS1B(S,2); CONS1B(S,3); } while (0)

__global__ __launch_bounds__(256)
__attribute__((amdgpu_waves_per_eu(3, 3)))   // grid = exactly 3 blocks/CU; stop the
                                             // allocator from chasing 8 waves/EU
void box_kernel(const float* __restrict__ x, float* __restrict__ out) {
    __shared__ float4 hring[9][256];   // 36 KB; every slot private to its thread

    const int tid = threadIdx.x;

    // XCD-aware bijective swizzle (768 % 8 == 0): each XCD owns 6 whole
    // images -> vertically-adjacent strips share their halo rows in one L2.
    const int lin  = blockIdx.x + NSTRIP * blockIdx.y;
    const int nblk = NSTRIP * gridDim.y;          // 768
    const int cpx  = nblk >> 3;                   // 96
    const int swz  = (lin & 7) * cpx + (lin >> 3);
    const int strip = swz & (NSTRIP - 1);
    const int img   = swz / NSTRIP;

    const int r0 = strip * BH;
    const int c  = tid * 4;
    const bool first = (tid == 0);
    const bool last  = (tid == 255);
    const float4 z4 = make_float4(0.f, 0.f, 0.f, 0.f);

    const float* __restrict__ xin = x + (size_t)img * (HH * WW);
    float* __restrict__ o = out + (size_t)img * (HH * WW);

    // per-column horizontal counts (constant over rows)
    float sw[4];
#pragma unroll
    for (int j = 0; j < 4; ++j) {
        int cc = c + j;
        int lo = cc - RAD < 0 ? 0 : cc - RAD;
        int hi = cc + RAD > WW - 1 ? WW - 1 : cc + RAD;
        sw[j] = 1.0f / (float)(hi - lo + 1);
    }

    // ---- prime: rows r0-5 .. r0+3 -> ring slots 0..8, all accumulated ----
    float vs0 = 0.f, vs1 = 0.f, vs2 = 0.f, vs3 = 0.f;
#pragma unroll
    for (int k = 0; k < 9; ++k) {
        int rr = r0 - RAD - 1 + k;               // <= r0+3 <= 1023 always
        HS h;
        if (rr >= 0) {
            float4 a, b, d;
            LOADROW(a, b, d, xin + (size_t)rr * WW);
            h = hcompute(a, b, d);
        } else { h.h0 = h.h1 = h.h2 = h.h3 = 0.f; }
        hring[k][tid] = make_float4(h.h0, h.h1, h.h2, h.h3);
        vs0 += h.h0; vs1 += h.h1; vs2 += h.h2; vs3 += h.h3;
    }

    const bool interior = (r0 >= RAD) && (r0 + BH + RAD <= HH);

    // two register sets: 24 float4 = 96 VGPR of in-flight loads (4-8 rows ahead)
    float4 aA0, bA0, dA0, aA1, bA1, dA1, aA2, bA2, dA2, aA3, bA3, dA3;
    float4 aB0, bB0, dB0, aB1, bB1, dB1, aB2, bB2, dB2, aB3, bB3, dB3;

    float* op = o + (size_t)r0 * WW + c;
    int slot = 0;

    if (interior) {
        const float w0 = sw[0] * (1.0f / 9.0f);
        const float w1 = sw[1] * (1.0f / 9.0f);
        const float w2 = sw[2] * (1.0f / 9.0f);
        const float w3 = sw[3] * (1.0f / 9.0f);

        const float* rowp = xin + (size_t)(r0 + RAD) * WW;
        LOADG(A);                                 // group 0: rows r0+4..r0+7
        // 16 groups of 4 rows; loads reach r0+67 <= 963 for last interior strip
#pragma unroll 1
        for (int it = 0; it < 7; ++it) {
            LOADG(B); CONSG(A);                   // issue next group, then consume
            LOADG(A); CONSG(B);
        }
        LOADG(B); CONSG(A);
        CONSG(B);
    } else {
        // boundary strips (r0=0, r0=960): clamped loads, per-row count.
        int prow = r0 + RAD;
        int r = r0;
        LOADGB(A);
#pragma unroll 1
        for (int it = 0; it < 7; ++it) {
            LOADGB(B); CONSGB(A);
            LOADGB(A); CONSGB(B);
        }
        LOADGB(B); CONSGB(A);
        CONSGB(B);
    }
}

extern "C" void kernel_launch(void* const* d_in, const int* in_sizes, int n_in,
                              void* d_out, int out_size, void* d_ws, size_t ws_size,
                              hipStream_t stream) {
    const float* x = (const float*)d_in[0];
    float* out = (float*)d_out;
    int n_images = in_sizes[0] / (HH * WW);   // 16*3 = 48
    dim3 grid(NSTRIP, n_images);              // 16 x 48 = 768 blocks
    dim3 block(256);
    box_kernel<<<grid, block, 0, stream>>>(x, out);
}